// Round 8
// baseline (926.518 us; speedup 1.0000x reference)
//
#include <hip/hip_runtime.h>

typedef unsigned short u16;
typedef __attribute__((ext_vector_type(4))) float f32x4;
typedef __attribute__((ext_vector_type(2))) float f32x2;
typedef __attribute__((ext_vector_type(8))) short s16x8;

__device__ __forceinline__ u16 f2bf(float f) {
    union { float f; unsigned u; } c; c.f = f;
    return (u16)((c.u + 0x7fffu + ((c.u >> 16) & 1u)) >> 16);
}
__device__ __forceinline__ float bf2f(u16 u) {
    union { unsigned u; float f; } c; c.u = ((unsigned)u) << 16; return c.f;
}
__device__ __forceinline__ unsigned pk2(float a, float b) {
    return (unsigned)f2bf(a) | ((unsigned)f2bf(b) << 16);
}
__device__ __forceinline__ float sigm(float x) { return 1.0f / (1.0f + __expf(-x)); }

// packed 2-wide bf16-unpack + FMA; vector fma invites v_pk_fma_f32 (VOP3P).
__device__ __forceinline__ void fma2v(unsigned xv, f32x2 wp, f32x2& a) {
    union { float f; unsigned u; } lo, hi;
    lo.u = xv << 16; hi.u = xv & 0xFFFF0000u;
    f32x2 xp = {lo.f, hi.f};
    a = __builtin_elementwise_fma(xp, wp, a);
}

// async global->LDS, 16B/lane (dense gemm for L4/L5)
__device__ __forceinline__ void load16_g2l(const void* g, void* l) {
    __builtin_amdgcn_global_load_lds(
        (const __attribute__((address_space(1))) unsigned int*)(unsigned long long)g,
        (__attribute__((address_space(3))) unsigned int*)(unsigned int)(unsigned long long)l,
        16, 0, 0);
}

// R6 proved padding cache-neutral; revert to 2048 so gather addressing is a
// single <<11 instead of shift+shift+add.
#define GSTR 2048

// ======================= prep helpers: transposes + find + conv ==============
__device__ void d_transpF(const float* __restrict__ in, u16* __restrict__ out,
                          int ldo, int Cc, int bx, int by, float (*t)[65]) {
    const int r0 = by * 64, c0 = bx * 64;
    const int tid = threadIdx.x;
#pragma unroll
    for (int i = 0; i < 4; i++) {
        int idx = tid + i * 256;           // 1024 = 64 rows x 16 float4
        int rr = idx >> 4, c4 = (idx & 15) * 4;
        float4 v = *(const float4*)(in + (size_t)(r0 + rr) * Cc + c0 + c4);
        t[rr][c4 + 0] = v.x; t[rr][c4 + 1] = v.y;
        t[rr][c4 + 2] = v.z; t[rr][c4 + 3] = v.w;
    }
    __syncthreads();
#pragma unroll
    for (int i = 0; i < 8; i++) {
        int idx = tid + i * 256;           // 2048 = 64 cols x 32 row-pairs
        int cc = idx >> 5, rp = (idx & 31) * 2;
        unsigned p = pk2(t[rp][cc], t[rp + 1][cc]);
        *(unsigned*)(out + (size_t)(c0 + cc) * ldo + r0 + rp) = p;
    }
}

// One block scans ONE mask [n][32] fully; each one-hot column has exactly one
// nonzero -> ~32 LDS atomics total. Replaces 32 redundant full-mask scans.
__device__ void d_find32(const float* __restrict__ mask, int n,
                         int* __restrict__ outp, int* fidx) {
    const int tid = threadIdx.x;
    if (tid < 32) fidx[tid] = 0;
    __syncthreads();
    for (int i = tid; i < n; i += 256) {
        const float4* row = (const float4*)(mask + (size_t)i * 32);
#pragma unroll
        for (int q = 0; q < 8; q++) {
            float4 v = row[q];
            if (v.x != 0.f) atomicMax(&fidx[q * 4 + 0], i);
            if (v.y != 0.f) atomicMax(&fidx[q * 4 + 1], i);
            if (v.z != 0.f) atomicMax(&fidx[q * 4 + 2], i);
            if (v.w != 0.f) atomicMax(&fidx[q * 4 + 3], i);
        }
    }
    __syncthreads();
    if (tid < 32) outp[tid] = fidx[tid];
}

__device__ void d_conv(const float* __restrict__ in, u16* __restrict__ out,
                       int bid, unsigned n8) {
    unsigned i = bid * 256u + threadIdx.x;
    if (i >= n8) return;
    float4 a = ((const float4*)in)[2 * i];
    float4 b = ((const float4*)in)[2 * i + 1];
    uint4 o;
    o.x = pk2(a.x, a.y); o.y = pk2(a.z, a.w);
    o.z = pk2(b.x, b.y); o.w = pk2(b.z, b.w);
    ((uint4*)out)[i] = o;
}

// ======================= ELL build v6: row split across 4 waves ==============
template <int SUBC>
__device__ void d_ell_row(const float* __restrict__ M, const float* __restrict__ W,
                          unsigned* __restrict__ ell, int* __restrict__ cnt,
                          int PAD, int row, int* __restrict__ lds) {
    const int lane = threadIdx.x & 63;
    const int wv = threadIdx.x >> 6;
    const int C = SUBC * 4096;
    const float4* mrow = (const float4*)(M + (size_t)row * C);
    const float4* wrow = (const float4*)(W + (size_t)row * C);
    unsigned* erow = ell + (size_t)row * PAD;

    float4 m[SUBC * 4];
#pragma unroll
    for (int k = 0; k < SUBC * 4; k++) {
        int sc = k >> 2, i = k & 3;
        m[k] = mrow[(wv * SUBC + sc) * 256 + lane + i * 64];
    }
    unsigned bits[SUBC];
    int total = 0;
#pragma unroll
    for (int sc = 0; sc < SUBC; sc++) {
        unsigned b = 0;
#pragma unroll
        for (int i = 0; i < 4; i++) {
            const float4 mm = m[sc * 4 + i];
            if (mm.x != 0.f) b |= 1u << (4 * i);
            if (mm.y != 0.f) b |= 2u << (4 * i);
            if (mm.z != 0.f) b |= 4u << (4 * i);
            if (mm.w != 0.f) b |= 8u << (4 * i);
        }
        bits[sc] = b;
        total += __popc(b);
    }
    float4 w[SUBC * 4];
#pragma unroll
    for (int k = 0; k < SUBC * 4; k++) {
        int sc = k >> 2, i = k & 3;
        if ((bits[sc] >> (4 * i)) & 0xFu)
            w[k] = wrow[(wv * SUBC + sc) * 256 + lane + i * 64];
    }
    int pre = total;
#pragma unroll
    for (int off = 1; off < 64; off <<= 1) {
        int t = __shfl_up(pre, off, 64);
        if (lane >= off) pre += t;
    }
    if (lane == 63) lds[wv] = pre;
    __syncthreads();
    int base = 0;
#pragma unroll
    for (int v = 0; v < 3; v++) if (v < wv) base += lds[v];
    int s = base + pre - total;
    __asm__ volatile("" ::: "memory");
#pragma unroll
    for (int sc = 0; sc < SUBC; sc++) {
        const unsigned b = bits[sc];
        const int f4b = (wv * SUBC + sc) * 256;
#pragma unroll
        for (int i = 0; i < 4; i++) {
            if ((b >> (4 * i)) & 0xFu) {
                const float4 wv4 = w[sc * 4 + i];
                int c = (f4b + lane + i * 64) * 4;
                if (b & (1u << (4 * i))) { if (s < PAD) erow[s] = ((unsigned)f2bf(wv4.x) << 16) | (unsigned)(c + 0); s++; }
                if (b & (2u << (4 * i))) { if (s < PAD) erow[s] = ((unsigned)f2bf(wv4.y) << 16) | (unsigned)(c + 1); s++; }
                if (b & (4u << (4 * i))) { if (s < PAD) erow[s] = ((unsigned)f2bf(wv4.z) << 16) | (unsigned)(c + 2); s++; }
                if (b & (8u << (4 * i))) { if (s < PAD) erow[s] = ((unsigned)f2bf(wv4.w) << 16) | (unsigned)(c + 3); s++; }
            }
        }
    }
    if (threadIdx.x == 0) {
        int rt = lds[0] + lds[1] + lds[2] + lds[3];
        cnt[row] = rt > PAD ? PAD : rt;
    }
}

// ======================= prep part: ELL rows + misc, interleaved =============
// misc ids: 0..8191 transposes, 8192..8195 find32, 8196..8451 convW4,
// 8452..8483 convW5. mcount total 8484.
__global__ __launch_bounds__(256) void prep_part(
    int ebase, int ecount, int mbase, int mcount,
    const float* __restrict__ Adj, const float* __restrict__ W1,
    unsigned* __restrict__ ell1, int* __restrict__ cnt1,
    const float* __restrict__ edge, const float* __restrict__ W2,
    unsigned* __restrict__ ell2, int* __restrict__ cnt2,
    const float* __restrict__ path, const float* __restrict__ W3,
    unsigned* __restrict__ ell3, int* __restrict__ cnt3,
    const float* __restrict__ xg_f, const float* __restrict__ xinv_f,
    const float* __restrict__ xcv_f,
    u16* __restrict__ xTg, u16* __restrict__ xinvT, u16* __restrict__ xcvT,
    const float* __restrict__ m0, const float* __restrict__ m1,
    const float* __restrict__ m2, const float* __restrict__ m3,
    int* __restrict__ idx,
    const float* __restrict__ W4, u16* __restrict__ w4b,
    const float* __restrict__ W5, u16* __restrict__ w5b) {
    __shared__ float tile[64][65];
    const long long T = ecount + mcount, E = ecount;
    const int b = blockIdx.x;
    const int ea = (int)(((long long)b * E) / T);
    const int eb2 = (int)(((long long)(b + 1) * E) / T);
    if (eb2 > ea) {
        int id = ebase + ea;
        if (id < 4096) { d_ell_row<1>(Adj, W1, ell1, cnt1, 256, id, (int*)tile); return; }
        id -= 4096;
        if (id < 8192) { d_ell_row<1>(edge, W2, ell2, cnt2, 96, id, (int*)tile); return; }
        d_ell_row<2>(path, W3, ell3, cnt3, 320, id - 8192, (int*)tile);
        return;
    }
    int id = mbase + (b - ea);
    if (id < 2048) { d_transpF(xg_f, xTg, GSTR, 4096, id & 63, id >> 6, tile); return; }
    id -= 2048;
    if (id < 2048) { d_transpF(xinv_f, xinvT, 2048, 4096, id & 63, id >> 6, tile); return; }
    id -= 2048;
    if (id < 4096) { d_transpF(xcv_f, xcvT, 2048, 8192, id & 127, id >> 7, tile); return; }
    id -= 4096;
    if (id < 4) {
        const float* mk; int n;
        if (id == 0)      { mk = m0; n = 4096; }
        else if (id == 1) { mk = m1; n = 4096; }
        else if (id == 2) { mk = m2; n = 8192; }
        else              { mk = m3; n = 2048; }
        d_find32(mk, n, idx + id * 32, (int*)tile);
        return;
    }
    id -= 4;
    if (id < 256) { d_conv(W4, w4b, id, 65536u); return; }
    id -= 256;
    d_conv(W5, w5b, id, 8192u);
}

// ---- sparse layer (L1/L2): wave = row j, lanes = batch slice ---------------
// Packed f32x2 accumulators -> v_pk_fma_f32. Accumulation order per element
// unchanged (same adds, same order) -> numerics identical.
template <int BPL, int LAYER, int XSTR, int ISTR, int OSTR>
__global__ __launch_bounds__(256) void spmm(const unsigned* __restrict__ ell,
                                            const int* __restrict__ cnt,
                                            const u16* __restrict__ xT,
                                            u16* __restrict__ outT,
                                            const float* __restrict__ bias,
                                            const float* __restrict__ c1a,
                                            const float* __restrict__ c1b,
                                            const float* __restrict__ c2a,
                                            const float* __restrict__ c2b,
                                            const u16* __restrict__ invT,
                                            const int* __restrict__ gidx,
                                            u16* __restrict__ gdst,
                                            int PAD) {
    const int lane = threadIdx.x & 63;
    const int wv = __builtin_amdgcn_readfirstlane((int)(threadIdx.x >> 6));
    const int j = blockIdx.x * 4 + wv;
    const int b0 = blockIdx.y * (64 * BPL) + lane * BPL;

    const unsigned* ep = ell + (size_t)j * PAD;
    int len = cnt[j];
    if (len > PAD) len = PAD;

    f32x2 acc2[BPL / 2];
#pragma unroll
    for (int i = 0; i < BPL / 2; i++) acc2[i] = (f32x2){0.f, 0.f};

    const int nfull = len >> 3;
    unsigned eA[8];
    if (nfull > 0) {
#pragma unroll
        for (int t = 0; t < 8; t++) eA[t] = ep[t];
    }
    for (int g = 0; g < nfull; g++) {
        unsigned eB[8];
        const bool more = (g + 1 < nfull);
        if (more) {
#pragma unroll
            for (int t = 0; t < 8; t++) eB[t] = ep[(g + 1) * 8 + t];
        }
        uint2 xv[8];
#pragma unroll
        for (int t = 0; t < 8; t++)
            xv[t] = *(const uint2*)(xT + (size_t)(eA[t] & 0xFFFFu) * XSTR + b0);
#pragma unroll
        for (int t = 0; t < 8; t++) {
            union { float f; unsigned u; } w; w.u = (eA[t] >> 16) << 16;
            f32x2 wp = {w.f, w.f};
            fma2v(xv[t].x, wp, acc2[0]);
            fma2v(xv[t].y, wp, acc2[1]);
        }
        if (more) {
#pragma unroll
            for (int t = 0; t < 8; t++) eA[t] = eB[t];
        }
    }
    for (int s = nfull * 8; s < len; ++s) {
        unsigned e = ep[s];
        union { float f; unsigned u; } w; w.u = (e >> 16) << 16;
        f32x2 wp = {w.f, w.f};
        const u16* xp = xT + (size_t)(e & 0xFFFFu) * XSTR + b0;
        uint2 xv = *(const uint2*)xp;
        fma2v(xv.x, wp, acc2[0]); fma2v(xv.y, wp, acc2[1]);
    }

    float acc[BPL];
#pragma unroll
    for (int i = 0; i < BPL / 2; i++) { acc[2 * i] = acc2[i].x; acc[2 * i + 1] = acc2[i].y; }

    const float bi = bias[j];
    float c1 = 0.f;
    if (c1a) { c1 = c1a[j]; if (c1b) c1 *= c1b[j]; }
    float c2 = 1.f;
    if (c2a) { c2 = c2a[j]; if (c2b) c2 *= c2b[j]; }

    float v[BPL];
#pragma unroll
    for (int i = 0; i < BPL; i++) v[i] = sigm(acc[i] + bi) * c2;
    if (invT) {
        const unsigned long long* ip = (const unsigned long long*)(invT + (size_t)j * ISTR + b0);
#pragma unroll
        for (int h = 0; h < BPL / 4; h++) {
            unsigned long long iv = __builtin_nontemporal_load(ip + h);
            unsigned lo = (unsigned)iv, hi = (unsigned)(iv >> 32);
            union { float f; unsigned u; } g0, g1, g2, g3;
            g0.u = lo << 16; g1.u = lo & 0xFFFF0000u;
            g2.u = hi << 16; g3.u = hi & 0xFFFF0000u;
            v[4 * h + 0] += g0.f * c1; v[4 * h + 1] += g1.f * c1;
            v[4 * h + 2] += g2.f * c1; v[4 * h + 3] += g3.f * c1;
        }
    }
    unsigned long long pkv[BPL / 4];
#pragma unroll
    for (int h = 0; h < BPL / 4; h++)
        pkv[h] = (unsigned long long)pk2(v[4 * h + 0], v[4 * h + 1])
               | ((unsigned long long)pk2(v[4 * h + 2], v[4 * h + 3]) << 32);
    unsigned long long* op = (unsigned long long*)(outT + (size_t)j * OSTR + b0);
#pragma unroll
    for (int h = 0; h < BPL / 4; h++) __builtin_nontemporal_store(pkv[h], op + h);

    if (gdst) {
        for (int t = 0; t < 32; t++) {
            if (gidx[t] == j) {
                unsigned long long* gp = (unsigned long long*)(gdst + t * 2048 + b0);
#pragma unroll
                for (int h = 0; h < BPL / 4; h++) gp[h] = pkv[h];
            }
        }
    }
}

// ---- L3 sparse layer, slice-phased: grid (512 j-blocks, 16 batch slices) ----
template <int XSTR>
__global__ __launch_bounds__(256) void spmm_ph(const unsigned* __restrict__ ell,
                                               const int* __restrict__ cnt,
                                               const u16* __restrict__ xT,
                                               u16* __restrict__ outT,       // [2048][2048]
                                               const float* __restrict__ bias,
                                               const float* __restrict__ scale,
                                               const int* __restrict__ gidx,
                                               u16* __restrict__ gdst,
                                               int PAD) {
    const int lane = threadIdx.x & 63;
    const int wv = __builtin_amdgcn_readfirstlane((int)(threadIdx.x >> 6));
    const int j = blockIdx.x * 4 + wv;
    const int b0 = blockIdx.y * 128 + lane * 2;

    const unsigned* ep = ell + (size_t)j * PAD;
    int len = cnt[j];
    if (len > PAD) len = PAD;

    f32x2 a2 = (f32x2){0.f, 0.f};
    const int nfull = len >> 4;
    unsigned eA[16];
    if (nfull > 0) {
#pragma unroll
        for (int t = 0; t < 16; t++) eA[t] = ep[t];
    }
    for (int g = 0; g < nfull; g++) {
        unsigned eB[16];
        const bool more = (g + 1 < nfull);
        if (more) {
#pragma unroll
            for (int t = 0; t < 16; t++) eB[t] = ep[(g + 1) * 16 + t];
        }
        unsigned xv[16];
#pragma unroll
        for (int t = 0; t < 16; t++)
            xv[t] = *(const unsigned*)(xT + (size_t)(eA[t] & 0xFFFFu) * XSTR + b0);
#pragma unroll
        for (int t = 0; t < 16; t++) {
            union { float f; unsigned u; } w; w.u = (eA[t] >> 16) << 16;
            f32x2 wp = {w.f, w.f};
            fma2v(xv[t], wp, a2);
        }
        if (more) {
#pragma unroll
            for (int t = 0; t < 16; t++) eA[t] = eB[t];
        }
    }
    for (int s = nfull * 16; s < len; ++s) {
        unsigned e = ep[s];
        union { float f; unsigned u; } w; w.u = (e >> 16) << 16;
        f32x2 wp = {w.f, w.f};
        unsigned xv = *(const unsigned*)(xT + (size_t)(e & 0xFFFFu) * XSTR + b0);
        fma2v(xv, wp, a2);
    }

    const float bi = bias[j];
    const float sc = scale[j];
    const unsigned pk = pk2(sigm(a2.x + bi) * sc, sigm(a2.y + bi) * sc);
    *(unsigned*)(outT + ((size_t)j << 11) + b0) = pk;

    if (gdst) {
        for (int t = 0; t < 32; t++) {
            if (gidx[t] == j)
                *(unsigned*)(gdst + t * 2048 + b0) = pk;
        }
    }
}

// ---- gather into transposed kept array [32][2048] from f32 source ----------
__global__ __launch_bounds__(256) void gatherFT(const float* __restrict__ src, int ld,
                                                const int* __restrict__ idx,
                                                u16* __restrict__ dstT) {
    int i = blockIdx.x * 256 + threadIdx.x;  // 65536
    int kk = i >> 11, b = i & 2047;
    dstT[i] = f2bf(src[(size_t)b * ld + idx[kk]]);
}

// ---- bf16 [Rr][Cc] -> bf16 transposed [Cc][Rr] -----------------------------
__global__ __launch_bounds__(256) void transpB(const u16* __restrict__ in,
                                               u16* __restrict__ out, int Rr, int Cc) {
    __shared__ u16 t[64][66];
    const int r0 = blockIdx.y * 64, c0 = blockIdx.x * 64;
    const int tid = threadIdx.x;
#pragma unroll
    for (int i = 0; i < 16; i++) {
        int idx = tid + i * 256;
        int rr = idx >> 6, cc = idx & 63;
        t[rr][cc] = in[(size_t)(r0 + rr) * Cc + c0 + cc];
    }
    __syncthreads();
#pragma unroll
    for (int i = 0; i < 16; i++) {
        int idx = tid + i * 256;
        int cc = idx >> 6, rr = idx & 63;
        out[(size_t)(c0 + cc) * Rr + r0 + rr] = t[rr][cc];
    }
}

// ---- dense NT GEMM, used for small L4/L5 only ------------------------------
template <int WR, int WC, int MF, int NF, int KC, int WPE>
__global__ __launch_bounds__(WR * WC * 64, WPE)
void gemm_t(const u16* __restrict__ A, const u16* __restrict__ W,
            u16* __restrict__ Out, const float* __restrict__ bias, int N, int K) {
    constexpr int NTHR = WR * WC * 64;
    constexpr int BM = WR * MF * 16;
    constexpr int BN = WC * NF * 16;
    constexpr int BK = KC * 32;
    constexpr int CPR = KC * 4;
    constexpr int MSK = CPR - 1;
    constexpr int CA = BM * CPR / NTHR;
    constexpr int CB = BN * CPR / NTHR;
    constexpr int L  = CA + CB;

    __shared__ u16 At[2][BM * BK];
    __shared__ u16 Bt[2][BN * BK];

    const int tid = threadIdx.x;
    const int lane = tid & 63;
    const int wave = tid >> 6;
    const int wr = wave / WC, wc = wave % WC;
    const int tn = blockIdx.x, tm = blockIdx.y;
    const int r16 = lane & 15;
    const int q = lane >> 4;

    const u16* aSrc[CA]; int aDst[CA];
#pragma unroll
    for (int j = 0; j < CA; j++) {
        int c = tid + j * NTHR;
        int r = c / CPR, p = c - r * CPR;
        aSrc[j] = A + (size_t)(tm * BM + r) * K + (p ^ (r & MSK)) * 8;
        aDst[j] = c * 8;
    }
    const u16* bSrc[CB]; int bDst[CB];
#pragma unroll
    for (int j = 0; j < CB; j++) {
        int c = tid + j * NTHR;
        int r = c / CPR, p = c - r * CPR;
        bSrc[j] = W + (size_t)(tn * BN + r) * K + (p ^ (r & MSK)) * 8;
        bDst[j] = c * 8;
    }
    int aRd[MF][KC], bRd[NF][KC];
#pragma unroll
    for (int mi = 0; mi < MF; mi++)
#pragma unroll
        for (int kc = 0; kc < KC; kc++)
            aRd[mi][kc] = (wr * MF * 16 + mi * 16 + r16) * BK + (((kc * 4 + q) ^ (r16 & MSK)) << 3);
#pragma unroll
    for (int ni = 0; ni < NF; ni++)
#pragma unroll
        for (int kc = 0; kc < KC; kc++)
            bRd[ni][kc] = (wc * NF * 16 + ni * 16 + r16) * BK + (((kc * 4 + q) ^ (r16 & MSK)) << 3);

    const int nIter = K / BK;

#define ISSUE(slot, it_)                                              \
    do {                                                              \
        const int k0_ = (it_) * BK;                                   \
        _Pragma("unroll")                                             \
        for (int j = 0; j < CA; j++)                                  \
            load16_g2l(aSrc[j] + k0_, &At[slot][aDst[j]]);            \
        _Pragma("unroll")                                             \
        for (int j = 0; j < CB; j++)                                  \
            load16_g2l(bSrc[j] + k0_, &Bt[slot][bDst[j]]);            \
    } while (0)

    ISSUE(0, 0);
    if (nIter > 1) ISSUE(1, 1);

    f32x4 acc[MF][NF];
#pragma unroll
    for (int i = 0; i < MF; i++)
#pragma unroll
        for (int j = 0; j < NF; j++) acc[i][j] = (f32x4){0.f, 0.f, 0.f, 0.f};

    for (int it = 0; it < nIter; ++it) {
        const int s = it & 1;
        if (it + 1 < nIter) __builtin_amdgcn_s_waitcnt(0xF70 | L);
        else                __builtin_amdgcn_s_waitcnt(0xF70);
        __asm__ volatile("" ::: "memory");
        __builtin_amdgcn_s_barrier();
        __asm__ volatile("" ::: "memory");

        s16x8 af[KC][MF], bfr[KC][NF];
#pragma unroll
        for (int kc = 0; kc < KC; kc++) {
#pragma unroll
            for (int mi = 0; mi < MF; mi++) af[kc][mi] = *(const s16x8*)(&At[s][aRd[mi][kc]]);
#pragma unroll
            for (int ni = 0; ni < NF; ni++) bfr[kc][ni] = *(const s16x8*)(&Bt[s][bRd[ni][kc]]);
        }
        __asm__ volatile("" ::: "memory");
        __builtin_amdgcn_s_waitcnt(0xC07F);
        __builtin_amdgcn_s_barrier();
        __asm__ volatile("" ::: "memory");

        if (it + 2 < nIter) ISSUE(s, it + 2);

#pragma unroll
        for (int kc = 0; kc < KC; kc++)
#pragma unroll
            for (int mi = 0; mi < MF; mi++)
#pragma unroll
                for (int ni = 0; ni < NF; ni++)
                    acc[mi][ni] = __builtin_amdgcn_mfma_f32_16x16x32_bf16(af[kc][mi], bfr[kc][ni], acc[mi][ni], 0, 0, 0);
    }
#undef ISSUE

#pragma unroll
    for (int ni = 0; ni < NF; ni++) {
        const int n = tn * BN + wc * NF * 16 + ni * 16 + r16;
        const float bi = bias ? bias[n] : 0.f;
#pragma unroll
        for (int mi = 0; mi < MF; mi++) {
#pragma unroll
            for (int rg = 0; rg < 4; rg++) {
                const int m = tm * BM + wr * MF * 16 + mi * 16 + q * 4 + rg;
                Out[(size_t)m * N + n] = f2bf(sigm(acc[mi][ni][rg] + bi));
            }
        }
    }
}

// ---- tail (fused xcat): lp = sig(xcat @ W6^T); out = (lp - mean) @ W7^T ----
__global__ __launch_bounds__(256) void tail_k(const u16* __restrict__ x5,
                                              const u16* __restrict__ kgT,
                                              const u16* __restrict__ kiT,
                                              const u16* __restrict__ kcT,
                                              const u16* __restrict__ kpT,
                                              const float* __restrict__ clinn,
                                              const float* __restrict__ W6,
                                              const float* __restrict__ W7,
                                              float* __restrict__ out) {
    __shared__ float xs[8 * 400];
    __shared__ float s1[4][8], s2[4][8], s3[4];
    const int tid = threadIdx.x;
    const int b0 = blockIdx.x * 8;
    for (int i = tid; i < 8 * 400; i += 256) {
        int r = i / 400, c = i - r * 400;
        int b = b0 + r;
        float v;
        if (c < 256)      v = bf2f(x5[b * 256 + c]);
        else if (c < 288) v = bf2f(kgT[(c - 256) * 2048 + b]);
        else if (c < 320) v = bf2f(kiT[(c - 288) * 2048 + b]);
        else if (c < 352) v = bf2f(kcT[(c - 320) * 2048 + b]);
        else if (c < 384) v = bf2f(kpT[(c - 352) * 2048 + b]);
        else              v = clinn[b * 16 + (c - 384)];
        xs[i] = v;
    }
    __syncthreads();
    const int j = tid;
    float acc[8];
#pragma unroll
    for (int r = 0; r < 8; r++) acc[r] = 0.f;
    const float4* wrow = (const float4*)(W6 + (size_t)j * 400);
    for (int c = 0; c < 100; c++) {
        float4 wv = wrow[c];
        const float* wp = (const float*)&wv;
#pragma unroll
        for (int t = 0; t < 4; t++) {
            float w = wp[t];
            int k = c * 4 + t;
#pragma unroll
            for (int r = 0; r < 8; r++) acc[r] += w * xs[r * 400 + k];
        }
    }
    const float w7j = W7[j];
    const int lane = tid & 63, wave = tid >> 6;
    float t3 = w7j;
#pragma unroll
    for (int off = 32; off > 0; off >>= 1) t3 += __shfl_down(t3, off, 64);
    if (lane == 0) s3[wave] = t3;
#pragma unroll
    for (int r = 0; r < 8; r++) {
        float lp = sigm(acc[r]);
        float t1 = lp, t2 = lp * w7j;
#pragma unroll
        for (int off = 32; off > 0; off >>= 1) {
            t1 += __shfl_down(t1, off, 64);
            t2 += __shfl_down(t2, off, 64);
        }
        if (lane == 0) { s1[wave][r] = t1; s2[wave][r] = t2; }
    }
    __syncthreads();
    if (tid < 8) {
        float S1 = s1[0][tid] + s1[1][tid] + s1[2][tid] + s1[3][tid];
        float S2 = s2[0][tid] + s2[1][tid] + s2[2][tid] + s2[3][tid];
        float SW = s3[0] + s3[1] + s3[2] + s3[3];
        out[b0 + tid] = S2 - (S1 * (1.f / 256.f)) * SW;
    }
}

// ---------------------------------------------------------------------------
extern "C" void kernel_launch(void* const* d_in, const int* in_sizes, int n_in,
                              void* d_out, int out_size, void* d_ws, size_t ws_size,
                              hipStream_t stream) {
    const float* x_gene   = (const float*)d_in[0];
    const float* x_invmea = (const float*)d_in[1];
    const float* x_curv   = (const float*)d_in[2];
    const float* clinn    = (const float*)d_in[3];
    const float* Adj      = (const float*)d_in[4];
    const float* edge_m   = (const float*)d_in[5];
    const float* path_m   = (const float*)d_in[6];
    const float* tg_mask  = (const float*)d_in[7];
    const float* ti_mask  = (const float*)d_in[8];
    const float* tc_mask  = (const float*)d_in[9];
    const float* tp_mask  = (const float*)d_in[10];
    const float* W1 = (const float*)d_in[11];  const float* b1 = (const float*)d_in[12];
    const float* W2 = (const float*)d_in[13];  const float* b2 = (const float*)d_in[14];
    const float* W3 = (const float*)d_in[15];  const float* b3 = (const float*)d_in[16];
    const float* W4 = (const float*)d_in[17];  const float* b4 = (const float*)d_in[18];
    const float* W5 = (const float*)d_in[19];  const float* b5 = (const float*)d_in[20];
    const float* W6 = (const float*)d_in[21];
    const float* W7 = (const float*)d_in[22];
    const float* mp11 = (const float*)d_in[23];
    const float* mp12 = (const float*)d_in[24];
    const float* mp1  = (const float*)d_in[25];
    const float* mp21 = (const float*)d_in[26];
    const float* mp22 = (const float*)d_in[27];
    const float* mp2  = (const float*)d_in[28];
    const float* mp3  = (const float*)d_in[29];

    char* ws = (char*)d_ws;
    const float* nulf = nullptr;
    float* out = (float*)d_out;

    u16*  xTg   = (u16*)(ws + 0);            // [4096][2048] (region sized for 2112)
    u16*  x3T   = (u16*)(ws + 0);            // [2048][2048] (after L1; xTg dead)
    u16*  xinvT = (u16*)(ws + 17301504);     // [4096][2048]
    u16*  xcvT  = (u16*)(ws + 34078720);     // [8192][2048]
    u16*  x1T   = (u16*)(ws + 67633152);     // [4096][2048]
    u16*  x2T   = (u16*)(ws + 84934656);     // [8192][2048]
    u16*  x3    = (u16*)(ws + 119537664);    // [2048][2048]
    unsigned* ell1 = (unsigned*)(ws + 127926272);  // 4 MiB
    unsigned* ell2 = (unsigned*)(ws + 132120576);  // 3 MiB
    unsigned* ell3 = (unsigned*)(ws + 135266304);  // 2.5 MiB
    int* cnt1 = (int*)(ws + 137887744);
    int* cnt2 = (int*)(ws + 137904128);
    int* cnt3 = (int*)(ws + 137936896);
    int* idxg = (int*)(ws + 137953280);      // 512 B (4 x 32 ints)
    int* idxi = idxg + 32;
    int* idxc = idxg + 64;
    int* idxp = idxg + 96;
    u16* kgT  = (u16*)(ws + 137957376);      // 128 KiB [32][2048]
    u16* kiT  = (u16*)(ws + 138088448);
    u16* kcT  = (u16*)(ws + 138219520);
    u16* kpT  = (u16*)(ws + 138350592);
    u16* w4b  = (u16*)(ws + 138481664);      // 1 MiB
    u16* w5b  = (u16*)(ws + 139530240);      // 128 KiB
    u16* x4   = (u16*)(ws + 139661312);      // 1 MiB
    u16* x5   = (u16*)(ws + 140709888);      // 1 MiB

    // ---- prep split into two halves (visibility; split cost ~0, R7) --------
    // ELL: 14336 rows; misc: 8484 blocks (find consolidated 128->4).
    prep_part<<<11410, 256, 0, stream>>>(
        0, 7168, 0, 4242,
        Adj, W1, ell1, cnt1, edge_m, W2, ell2, cnt2, path_m, W3, ell3, cnt3,
        x_gene, x_invmea, x_curv, xTg, xinvT, xcvT,
        tg_mask, ti_mask, tc_mask, tp_mask, idxg, W4, w4b, W5, w5b);
    prep_part<<<11410, 256, 0, stream>>>(
        7168, 7168, 4242, 4242,
        Adj, W1, ell1, cnt1, edge_m, W2, ell2, cnt2, path_m, W3, ell3, cnt3,
        x_gene, x_invmea, x_curv, xTg, xinvT, xcvT,
        tg_mask, ti_mask, tc_mask, tp_mask, idxg, W4, w4b, W5, w5b);
    gatherFT<<<256, 256, 0, stream>>>(x_gene, 4096, idxg, kgT);

    // ---- L1 (slice-phased, fused kiT gather) ----
    spmm<4, 1, GSTR, 2048, GSTR><<<dim3(1024, 8), 256, 0, stream>>>(
        ell1, cnt1, xTg, x1T, b1, mp11, mp1, mp12, mp1, xinvT, idxi, kiT, 256);
    // ---- L2 (slice-phased, fused kcT gather) ----
    spmm<4, 2, GSTR, 2048, GSTR><<<dim3(2048, 8), 256, 0, stream>>>(
        ell2, cnt2, x1T, x2T, b2, mp21, mp2, mp22, mp2, xcvT, idxc, kcT, 96);
    // ---- L3 (slice-phased, fused kpT gather) ----
    spmm_ph<GSTR><<<dim3(512, 16), 256, 0, stream>>>(ell3, cnt3, x2T, x3T, b3,
                                                     mp3, idxp, kpT, 320);
    transpB<<<dim3(32, 32), 256, 0, stream>>>(x3T, x3, 2048, 2048);

    // ---- L4/L5 dense ----
    gemm_t<2, 2, 2, 2, 2, 4><<<dim3(4, 32), 256, 0, stream>>>(x3, w4b, x4, b4, 256, 2048);
    gemm_t<2, 2, 2, 2, 2, 4><<<dim3(4, 32), 256, 0, stream>>>(x4, w5b, x5, b5, 256, 256);

    // ---- fused xcat + tail ----
    tail_k<<<256, 256, 0, stream>>>(x5, kgT, kiT, kcT, kpT, clinn, W6, W7, out);
}

// Round 9
// 826.527 us; speedup vs baseline: 1.1210x; 1.1210x over previous
//
#include <hip/hip_runtime.h>

typedef unsigned short u16;
typedef __attribute__((ext_vector_type(4))) float f32x4;
typedef __attribute__((ext_vector_type(2))) float f32x2;
typedef __attribute__((ext_vector_type(8))) short s16x8;

__device__ __forceinline__ u16 f2bf(float f) {
    union { float f; unsigned u; } c; c.f = f;
    return (u16)((c.u + 0x7fffu + ((c.u >> 16) & 1u)) >> 16);
}
__device__ __forceinline__ float bf2f(u16 u) {
    union { unsigned u; float f; } c; c.u = ((unsigned)u) << 16; return c.f;
}
__device__ __forceinline__ unsigned pk2(float a, float b) {
    return (unsigned)f2bf(a) | ((unsigned)f2bf(b) << 16);
}
__device__ __forceinline__ float sigm(float x) { return 1.0f / (1.0f + __expf(-x)); }

// packed 2-wide bf16-unpack + FMA; vector fma invites v_pk_fma_f32 (VOP3P).
__device__ __forceinline__ void fma2v(unsigned xv, f32x2 wp, f32x2& a) {
    union { float f; unsigned u; } lo, hi;
    lo.u = xv << 16; hi.u = xv & 0xFFFF0000u;
    f32x2 xp = {lo.f, hi.f};
    a = __builtin_elementwise_fma(xp, wp, a);
}

// async global->LDS, 16B/lane (dense gemm for L4/L5)
__device__ __forceinline__ void load16_g2l(const void* g, void* l) {
    __builtin_amdgcn_global_load_lds(
        (const __attribute__((address_space(1))) unsigned int*)(unsigned long long)g,
        (__attribute__((address_space(3))) unsigned int*)(unsigned int)(unsigned long long)l,
        16, 0, 0);
}

#define GSTR 2048

// ======================= prep helpers: transposes + find + conv ==============
__device__ void d_transpF(const float* __restrict__ in, u16* __restrict__ out,
                          int ldo, int Cc, int bx, int by, float (*t)[65]) {
    const int r0 = by * 64, c0 = bx * 64;
    const int tid = threadIdx.x;
#pragma unroll
    for (int i = 0; i < 4; i++) {
        int idx = tid + i * 256;           // 1024 = 64 rows x 16 float4
        int rr = idx >> 4, c4 = (idx & 15) * 4;
        float4 v = *(const float4*)(in + (size_t)(r0 + rr) * Cc + c0 + c4);
        t[rr][c4 + 0] = v.x; t[rr][c4 + 1] = v.y;
        t[rr][c4 + 2] = v.z; t[rr][c4 + 3] = v.w;
    }
    __syncthreads();
#pragma unroll
    for (int i = 0; i < 8; i++) {
        int idx = tid + i * 256;           // 2048 = 64 cols x 32 row-pairs
        int cc = idx >> 5, rp = (idx & 31) * 2;
        unsigned p = pk2(t[rp][cc], t[rp + 1][cc]);
        *(unsigned*)(out + (size_t)(c0 + cc) * ldo + r0 + rp) = p;
    }
}

// R9: reverted to parallel 128-block find (R8's 4-block consolidation created
// serial single-CU tails: prep halves 90 -> 145us, occ 59 -> 29%).
__device__ void d_find(const float* __restrict__ mask, int n, int* __restrict__ outp,
                       int* red, int k) {
    int best = -1;
    for (int i = threadIdx.x; i < n; i += 256)
        if (mask[(size_t)i * 32 + k] != 0.0f) best = i;
    red[threadIdx.x] = best;
    __syncthreads();
    for (int off = 128; off > 0; off >>= 1) {
        if (threadIdx.x < off) {
            int o = red[threadIdx.x + off];
            if (o > red[threadIdx.x]) red[threadIdx.x] = o;
        }
        __syncthreads();
    }
    if (threadIdx.x == 0) *outp = red[0] < 0 ? 0 : red[0];
}

__device__ void d_conv(const float* __restrict__ in, u16* __restrict__ out,
                       int bid, unsigned n8) {
    unsigned i = bid * 256u + threadIdx.x;
    if (i >= n8) return;
    float4 a = ((const float4*)in)[2 * i];
    float4 b = ((const float4*)in)[2 * i + 1];
    uint4 o;
    o.x = pk2(a.x, a.y); o.y = pk2(a.z, a.w);
    o.z = pk2(b.x, b.y); o.w = pk2(b.z, b.w);
    ((uint4*)out)[i] = o;
}

// ======================= ELL build v6: row split across 4 waves ==============
template <int SUBC>
__device__ void d_ell_row(const float* __restrict__ M, const float* __restrict__ W,
                          unsigned* __restrict__ ell, int* __restrict__ cnt,
                          int PAD, int row, int* __restrict__ lds) {
    const int lane = threadIdx.x & 63;
    const int wv = threadIdx.x >> 6;
    const int C = SUBC * 4096;
    const float4* mrow = (const float4*)(M + (size_t)row * C);
    const float4* wrow = (const float4*)(W + (size_t)row * C);
    unsigned* erow = ell + (size_t)row * PAD;

    float4 m[SUBC * 4];
#pragma unroll
    for (int k = 0; k < SUBC * 4; k++) {
        int sc = k >> 2, i = k & 3;
        m[k] = mrow[(wv * SUBC + sc) * 256 + lane + i * 64];
    }
    unsigned bits[SUBC];
    int total = 0;
#pragma unroll
    for (int sc = 0; sc < SUBC; sc++) {
        unsigned b = 0;
#pragma unroll
        for (int i = 0; i < 4; i++) {
            const float4 mm = m[sc * 4 + i];
            if (mm.x != 0.f) b |= 1u << (4 * i);
            if (mm.y != 0.f) b |= 2u << (4 * i);
            if (mm.z != 0.f) b |= 4u << (4 * i);
            if (mm.w != 0.f) b |= 8u << (4 * i);
        }
        bits[sc] = b;
        total += __popc(b);
    }
    float4 w[SUBC * 4];
#pragma unroll
    for (int k = 0; k < SUBC * 4; k++) {
        int sc = k >> 2, i = k & 3;
        if ((bits[sc] >> (4 * i)) & 0xFu)
            w[k] = wrow[(wv * SUBC + sc) * 256 + lane + i * 64];
    }
    int pre = total;
#pragma unroll
    for (int off = 1; off < 64; off <<= 1) {
        int t = __shfl_up(pre, off, 64);
        if (lane >= off) pre += t;
    }
    if (lane == 63) lds[wv] = pre;
    __syncthreads();
    int base = 0;
#pragma unroll
    for (int v = 0; v < 3; v++) if (v < wv) base += lds[v];
    int s = base + pre - total;
    __asm__ volatile("" ::: "memory");
#pragma unroll
    for (int sc = 0; sc < SUBC; sc++) {
        const unsigned b = bits[sc];
        const int f4b = (wv * SUBC + sc) * 256;
#pragma unroll
        for (int i = 0; i < 4; i++) {
            if ((b >> (4 * i)) & 0xFu) {
                const float4 wv4 = w[sc * 4 + i];
                int c = (f4b + lane + i * 64) * 4;
                if (b & (1u << (4 * i))) { if (s < PAD) erow[s] = ((unsigned)f2bf(wv4.x) << 16) | (unsigned)(c + 0); s++; }
                if (b & (2u << (4 * i))) { if (s < PAD) erow[s] = ((unsigned)f2bf(wv4.y) << 16) | (unsigned)(c + 1); s++; }
                if (b & (4u << (4 * i))) { if (s < PAD) erow[s] = ((unsigned)f2bf(wv4.z) << 16) | (unsigned)(c + 2); s++; }
                if (b & (8u << (4 * i))) { if (s < PAD) erow[s] = ((unsigned)f2bf(wv4.w) << 16) | (unsigned)(c + 3); s++; }
            }
        }
    }
    if (threadIdx.x == 0) {
        int rt = lds[0] + lds[1] + lds[2] + lds[3];
        cnt[row] = rt > PAD ? PAD : rt;
    }
}

// ======================= prep part: ELL rows + misc, interleaved =============
// misc ids: 0..8191 transposes, 8192..8319 find(128), 8320..8575 convW4,
// 8576..8607 convW5. mcount total 8608.
__global__ __launch_bounds__(256) void prep_part(
    int ebase, int ecount, int mbase, int mcount,
    const float* __restrict__ Adj, const float* __restrict__ W1,
    unsigned* __restrict__ ell1, int* __restrict__ cnt1,
    const float* __restrict__ edge, const float* __restrict__ W2,
    unsigned* __restrict__ ell2, int* __restrict__ cnt2,
    const float* __restrict__ path, const float* __restrict__ W3,
    unsigned* __restrict__ ell3, int* __restrict__ cnt3,
    const float* __restrict__ xg_f, const float* __restrict__ xinv_f,
    const float* __restrict__ xcv_f,
    u16* __restrict__ xTg, u16* __restrict__ xinvT, u16* __restrict__ xcvT,
    const float* __restrict__ m0, const float* __restrict__ m1,
    const float* __restrict__ m2, const float* __restrict__ m3,
    int* __restrict__ idx,
    const float* __restrict__ W4, u16* __restrict__ w4b,
    const float* __restrict__ W5, u16* __restrict__ w5b) {
    __shared__ float tile[64][65];
    const long long T = ecount + mcount, E = ecount;
    const int b = blockIdx.x;
    const int ea = (int)(((long long)b * E) / T);
    const int eb2 = (int)(((long long)(b + 1) * E) / T);
    if (eb2 > ea) {
        int id = ebase + ea;
        if (id < 4096) { d_ell_row<1>(Adj, W1, ell1, cnt1, 256, id, (int*)tile); return; }
        id -= 4096;
        if (id < 8192) { d_ell_row<1>(edge, W2, ell2, cnt2, 96, id, (int*)tile); return; }
        d_ell_row<2>(path, W3, ell3, cnt3, 320, id - 8192, (int*)tile);
        return;
    }
    int id = mbase + (b - ea);
    if (id < 2048) { d_transpF(xg_f, xTg, GSTR, 4096, id & 63, id >> 6, tile); return; }
    id -= 2048;
    if (id < 2048) { d_transpF(xinv_f, xinvT, 2048, 4096, id & 63, id >> 6, tile); return; }
    id -= 2048;
    if (id < 4096) { d_transpF(xcv_f, xcvT, 2048, 8192, id & 127, id >> 7, tile); return; }
    id -= 4096;
    if (id < 128) {
        const float* mk; int n;
        int which = id >> 5;
        if (which == 0)      { mk = m0; n = 4096; }
        else if (which == 1) { mk = m1; n = 4096; }
        else if (which == 2) { mk = m2; n = 8192; }
        else                 { mk = m3; n = 2048; }
        d_find(mk, n, idx + which * 32 + (id & 31), (int*)tile, id & 31);
        return;
    }
    id -= 128;
    if (id < 256) { d_conv(W4, w4b, id, 65536u); return; }
    id -= 256;
    d_conv(W5, w5b, id, 8192u);
}

// ---- sparse layer (L1/L2): wave = row j, lanes = batch slice ---------------
// BPL=8 (uint4 gathers): per-entry overhead (ELL reads, addressing, loop ctrl)
// amortized over 2x data. Per-(j,batch) accumulation order unchanged ->
// numerics bit-identical. Slice in blockIdx.y (slowest) = temporal phasing.
template <int BPL, int LAYER, int XSTR, int ISTR, int OSTR>
__global__ __launch_bounds__(256) void spmm(const unsigned* __restrict__ ell,
                                            const int* __restrict__ cnt,
                                            const u16* __restrict__ xT,
                                            u16* __restrict__ outT,
                                            const float* __restrict__ bias,
                                            const float* __restrict__ c1a,
                                            const float* __restrict__ c1b,
                                            const float* __restrict__ c2a,
                                            const float* __restrict__ c2b,
                                            const u16* __restrict__ invT,
                                            const int* __restrict__ gidx,
                                            u16* __restrict__ gdst,
                                            int PAD) {
    const int lane = threadIdx.x & 63;
    const int wv = __builtin_amdgcn_readfirstlane((int)(threadIdx.x >> 6));
    const int j = blockIdx.x * 4 + wv;
    const int b0 = blockIdx.y * (64 * BPL) + lane * BPL;

    const unsigned* ep = ell + (size_t)j * PAD;
    int len = cnt[j];
    if (len > PAD) len = PAD;

    f32x2 acc2[BPL / 2];
#pragma unroll
    for (int i = 0; i < BPL / 2; i++) acc2[i] = (f32x2){0.f, 0.f};

    const int nfull = len >> 3;
    unsigned eA[8];
    if (nfull > 0) {
#pragma unroll
        for (int t = 0; t < 8; t++) eA[t] = ep[t];
    }
    for (int g = 0; g < nfull; g++) {
        unsigned eB[8];
        const bool more = (g + 1 < nfull);
        if (more) {
#pragma unroll
            for (int t = 0; t < 8; t++) eB[t] = ep[(g + 1) * 8 + t];
        }
        if (BPL == 8) {
            uint4 xv[8];
#pragma unroll
            for (int t = 0; t < 8; t++)
                xv[t] = *(const uint4*)(xT + (size_t)(eA[t] & 0xFFFFu) * XSTR + b0);
#pragma unroll
            for (int t = 0; t < 8; t++) {
                union { float f; unsigned u; } w; w.u = (eA[t] >> 16) << 16;
                f32x2 wp = {w.f, w.f};
                fma2v(xv[t].x, wp, acc2[0]);
                fma2v(xv[t].y, wp, acc2[1]);
                fma2v(xv[t].z, wp, acc2[2]);
                fma2v(xv[t].w, wp, acc2[3]);
            }
        } else {
            uint2 xv[8];
#pragma unroll
            for (int t = 0; t < 8; t++)
                xv[t] = *(const uint2*)(xT + (size_t)(eA[t] & 0xFFFFu) * XSTR + b0);
#pragma unroll
            for (int t = 0; t < 8; t++) {
                union { float f; unsigned u; } w; w.u = (eA[t] >> 16) << 16;
                f32x2 wp = {w.f, w.f};
                fma2v(xv[t].x, wp, acc2[0]);
                fma2v(xv[t].y, wp, acc2[1]);
            }
        }
        if (more) {
#pragma unroll
            for (int t = 0; t < 8; t++) eA[t] = eB[t];
        }
    }
    for (int s = nfull * 8; s < len; ++s) {
        unsigned e = ep[s];
        union { float f; unsigned u; } w; w.u = (e >> 16) << 16;
        f32x2 wp = {w.f, w.f};
        const u16* xp = xT + (size_t)(e & 0xFFFFu) * XSTR + b0;
        if (BPL == 8) {
            uint4 xv = *(const uint4*)xp;
            fma2v(xv.x, wp, acc2[0]); fma2v(xv.y, wp, acc2[1]);
            fma2v(xv.z, wp, acc2[2]); fma2v(xv.w, wp, acc2[3]);
        } else {
            uint2 xv = *(const uint2*)xp;
            fma2v(xv.x, wp, acc2[0]); fma2v(xv.y, wp, acc2[1]);
        }
    }

    float acc[BPL];
#pragma unroll
    for (int i = 0; i < BPL / 2; i++) { acc[2 * i] = acc2[i].x; acc[2 * i + 1] = acc2[i].y; }

    const float bi = bias[j];
    float c1 = 0.f;
    if (c1a) { c1 = c1a[j]; if (c1b) c1 *= c1b[j]; }
    float c2 = 1.f;
    if (c2a) { c2 = c2a[j]; if (c2b) c2 *= c2b[j]; }

    float v[BPL];
#pragma unroll
    for (int i = 0; i < BPL; i++) v[i] = sigm(acc[i] + bi) * c2;
    if (invT) {
        const unsigned long long* ip = (const unsigned long long*)(invT + (size_t)j * ISTR + b0);
#pragma unroll
        for (int h = 0; h < BPL / 4; h++) {
            unsigned long long iv = __builtin_nontemporal_load(ip + h);
            unsigned lo = (unsigned)iv, hi = (unsigned)(iv >> 32);
            union { float f; unsigned u; } g0, g1, g2, g3;
            g0.u = lo << 16; g1.u = lo & 0xFFFF0000u;
            g2.u = hi << 16; g3.u = hi & 0xFFFF0000u;
            v[4 * h + 0] += g0.f * c1; v[4 * h + 1] += g1.f * c1;
            v[4 * h + 2] += g2.f * c1; v[4 * h + 3] += g3.f * c1;
        }
    }
    unsigned long long pkv[BPL / 4];
#pragma unroll
    for (int h = 0; h < BPL / 4; h++)
        pkv[h] = (unsigned long long)pk2(v[4 * h + 0], v[4 * h + 1])
               | ((unsigned long long)pk2(v[4 * h + 2], v[4 * h + 3]) << 32);
    unsigned long long* op = (unsigned long long*)(outT + (size_t)j * OSTR + b0);
#pragma unroll
    for (int h = 0; h < BPL / 4; h++) __builtin_nontemporal_store(pkv[h], op + h);

    if (gdst) {
        for (int t = 0; t < 32; t++) {
            if (gidx[t] == j) {
                unsigned long long* gp = (unsigned long long*)(gdst + t * 2048 + b0);
#pragma unroll
                for (int h = 0; h < BPL / 4; h++) gp[h] = pkv[h];
            }
        }
    }
}

// ---- L3 sparse layer, slice-phased: grid (512 j-blocks, 16 batch slices) ----
template <int XSTR>
__global__ __launch_bounds__(256) void spmm_ph(const unsigned* __restrict__ ell,
                                               const int* __restrict__ cnt,
                                               const u16* __restrict__ xT,
                                               u16* __restrict__ outT,       // [2048][2048]
                                               const float* __restrict__ bias,
                                               const float* __restrict__ scale,
                                               const int* __restrict__ gidx,
                                               u16* __restrict__ gdst,
                                               int PAD) {
    const int lane = threadIdx.x & 63;
    const int wv = __builtin_amdgcn_readfirstlane((int)(threadIdx.x >> 6));
    const int j = blockIdx.x * 4 + wv;
    const int b0 = blockIdx.y * 128 + lane * 2;

    const unsigned* ep = ell + (size_t)j * PAD;
    int len = cnt[j];
    if (len > PAD) len = PAD;

    f32x2 a2 = (f32x2){0.f, 0.f};
    const int nfull = len >> 4;
    unsigned eA[16];
    if (nfull > 0) {
#pragma unroll
        for (int t = 0; t < 16; t++) eA[t] = ep[t];
    }
    for (int g = 0; g < nfull; g++) {
        unsigned eB[16];
        const bool more = (g + 1 < nfull);
        if (more) {
#pragma unroll
            for (int t = 0; t < 16; t++) eB[t] = ep[(g + 1) * 16 + t];
        }
        unsigned xv[16];
#pragma unroll
        for (int t = 0; t < 16; t++)
            xv[t] = *(const unsigned*)(xT + (size_t)(eA[t] & 0xFFFFu) * XSTR + b0);
#pragma unroll
        for (int t = 0; t < 16; t++) {
            union { float f; unsigned u; } w; w.u = (eA[t] >> 16) << 16;
            f32x2 wp = {w.f, w.f};
            fma2v(xv[t], wp, a2);
        }
        if (more) {
#pragma unroll
            for (int t = 0; t < 16; t++) eA[t] = eB[t];
        }
    }
    for (int s = nfull * 16; s < len; ++s) {
        unsigned e = ep[s];
        union { float f; unsigned u; } w; w.u = (e >> 16) << 16;
        f32x2 wp = {w.f, w.f};
        unsigned xv = *(const unsigned*)(xT + (size_t)(e & 0xFFFFu) * XSTR + b0);
        fma2v(xv, wp, a2);
    }

    const float bi = bias[j];
    const float sc = scale[j];
    const unsigned pk = pk2(sigm(a2.x + bi) * sc, sigm(a2.y + bi) * sc);
    *(unsigned*)(outT + ((size_t)j << 11) + b0) = pk;

    if (gdst) {
        for (int t = 0; t < 32; t++) {
            if (gidx[t] == j)
                *(unsigned*)(gdst + t * 2048 + b0) = pk;
        }
    }
}

// ---- gather into transposed kept array [32][2048] from f32 source ----------
__global__ __launch_bounds__(256) void gatherFT(const float* __restrict__ src, int ld,
                                                const int* __restrict__ idx,
                                                u16* __restrict__ dstT) {
    int i = blockIdx.x * 256 + threadIdx.x;  // 65536
    int kk = i >> 11, b = i & 2047;
    dstT[i] = f2bf(src[(size_t)b * ld + idx[kk]]);
}

// ---- bf16 [Rr][Cc] -> bf16 transposed [Cc][Rr] -----------------------------
__global__ __launch_bounds__(256) void transpB(const u16* __restrict__ in,
                                               u16* __restrict__ out, int Rr, int Cc) {
    __shared__ u16 t[64][66];
    const int r0 = blockIdx.y * 64, c0 = blockIdx.x * 64;
    const int tid = threadIdx.x;
#pragma unroll
    for (int i = 0; i < 16; i++) {
        int idx = tid + i * 256;
        int rr = idx >> 6, cc = idx & 63;
        t[rr][cc] = in[(size_t)(r0 + rr) * Cc + c0 + cc];
    }
    __syncthreads();
#pragma unroll
    for (int i = 0; i < 16; i++) {
        int idx = tid + i * 256;
        int cc = idx >> 6, rr = idx & 63;
        out[(size_t)(c0 + cc) * Rr + r0 + rr] = t[rr][cc];
    }
}

// ---- dense NT GEMM, used for small L4/L5 only ------------------------------
template <int WR, int WC, int MF, int NF, int KC, int WPE>
__global__ __launch_bounds__(WR * WC * 64, WPE)
void gemm_t(const u16* __restrict__ A, const u16* __restrict__ W,
            u16* __restrict__ Out, const float* __restrict__ bias, int N, int K) {
    constexpr int NTHR = WR * WC * 64;
    constexpr int BM = WR * MF * 16;
    constexpr int BN = WC * NF * 16;
    constexpr int BK = KC * 32;
    constexpr int CPR = KC * 4;
    constexpr int MSK = CPR - 1;
    constexpr int CA = BM * CPR / NTHR;
    constexpr int CB = BN * CPR / NTHR;
    constexpr int L  = CA + CB;

    __shared__ u16 At[2][BM * BK];
    __shared__ u16 Bt[2][BN * BK];

    const int tid = threadIdx.x;
    const int lane = tid & 63;
    const int wave = tid >> 6;
    const int wr = wave / WC, wc = wave % WC;
    const int tn = blockIdx.x, tm = blockIdx.y;
    const int r16 = lane & 15;
    const int q = lane >> 4;

    const u16* aSrc[CA]; int aDst[CA];
#pragma unroll
    for (int j = 0; j < CA; j++) {
        int c = tid + j * NTHR;
        int r = c / CPR, p = c - r * CPR;
        aSrc[j] = A + (size_t)(tm * BM + r) * K + (p ^ (r & MSK)) * 8;
        aDst[j] = c * 8;
    }
    const u16* bSrc[CB]; int bDst[CB];
#pragma unroll
    for (int j = 0; j < CB; j++) {
        int c = tid + j * NTHR;
        int r = c / CPR, p = c - r * CPR;
        bSrc[j] = W + (size_t)(tn * BN + r) * K + (p ^ (r & MSK)) * 8;
        bDst[j] = c * 8;
    }
    int aRd[MF][KC], bRd[NF][KC];
#pragma unroll
    for (int mi = 0; mi < MF; mi++)
#pragma unroll
        for (int kc = 0; kc < KC; kc++)
            aRd[mi][kc] = (wr * MF * 16 + mi * 16 + r16) * BK + (((kc * 4 + q) ^ (r16 & MSK)) << 3);
#pragma unroll
    for (int ni = 0; ni < NF; ni++)
#pragma unroll
        for (int kc = 0; kc < KC; kc++)
            bRd[ni][kc] = (wc * NF * 16 + ni * 16 + r16) * BK + (((kc * 4 + q) ^ (r16 & MSK)) << 3);

    const int nIter = K / BK;

#define ISSUE(slot, it_)                                              \
    do {                                                              \
        const int k0_ = (it_) * BK;                                   \
        _Pragma("unroll")                                             \
        for (int j = 0; j < CA; j++)                                  \
            load16_g2l(aSrc[j] + k0_, &At[slot][aDst[j]]);            \
        _Pragma("unroll")                                             \
        for (int j = 0; j < CB; j++)                                  \
            load16_g2l(bSrc[j] + k0_, &Bt[slot][bDst[j]]);            \
    } while (0)

    ISSUE(0, 0);
    if (nIter > 1) ISSUE(1, 1);

    f32x4 acc[MF][NF];
#pragma unroll
    for (int i = 0; i < MF; i++)
#pragma unroll
        for (int j = 0; j < NF; j++) acc[i][j] = (f32x4){0.f, 0.f, 0.f, 0.f};

    for (int it = 0; it < nIter; ++it) {
        const int s = it & 1;
        if (it + 1 < nIter) __builtin_amdgcn_s_waitcnt(0xF70 | L);
        else                __builtin_amdgcn_s_waitcnt(0xF70);
        __asm__ volatile("" ::: "memory");
        __builtin_amdgcn_s_barrier();
        __asm__ volatile("" ::: "memory");

        s16x8 af[KC][MF], bfr[KC][NF];
#pragma unroll
        for (int kc = 0; kc < KC; kc++) {
#pragma unroll
            for (int mi = 0; mi < MF; mi++) af[kc][mi] = *(const s16x8*)(&At[s][aRd[mi][kc]]);
#pragma unroll
            for (int ni = 0; ni < NF; ni++) bfr[kc][ni] = *(const s16x8*)(&Bt[s][bRd[ni][kc]]);
        }
        __asm__ volatile("" ::: "memory");
        __builtin_amdgcn_s_waitcnt(0xC07F);
        __builtin_amdgcn_s_barrier();
        __asm__ volatile("" ::: "memory");

        if (it + 2 < nIter) ISSUE(s, it + 2);

#pragma unroll
        for (int kc = 0; kc < KC; kc++)
#pragma unroll
            for (int mi = 0; mi < MF; mi++)
#pragma unroll
                for (int ni = 0; ni < NF; ni++)
                    acc[mi][ni] = __builtin_amdgcn_mfma_f32_16x16x32_bf16(af[kc][mi], bfr[kc][ni], acc[mi][ni], 0, 0, 0);
    }
#undef ISSUE

#pragma unroll
    for (int ni = 0; ni < NF; ni++) {
        const int n = tn * BN + wc * NF * 16 + ni * 16 + r16;
        const float bi = bias ? bias[n] : 0.f;
#pragma unroll
        for (int mi = 0; mi < MF; mi++) {
#pragma unroll
            for (int rg = 0; rg < 4; rg++) {
                const int m = tm * BM + wr * MF * 16 + mi * 16 + q * 4 + rg;
                Out[(size_t)m * N + n] = f2bf(sigm(acc[mi][ni][rg] + bi));
            }
        }
    }
}

// ---- tail (fused xcat): lp = sig(xcat @ W6^T); out = (lp - mean) @ W7^T ----
__global__ __launch_bounds__(256) void tail_k(const u16* __restrict__ x5,
                                              const u16* __restrict__ kgT,
                                              const u16* __restrict__ kiT,
                                              const u16* __restrict__ kcT,
                                              const u16* __restrict__ kpT,
                                              const float* __restrict__ clinn,
                                              const float* __restrict__ W6,
                                              const float* __restrict__ W7,
                                              float* __restrict__ out) {
    __shared__ float xs[8 * 400];
    __shared__ float s1[4][8], s2[4][8], s3[4];
    const int tid = threadIdx.x;
    const int b0 = blockIdx.x * 8;
    for (int i = tid; i < 8 * 400; i += 256) {
        int r = i / 400, c = i - r * 400;
        int b = b0 + r;
        float v;
        if (c < 256)      v = bf2f(x5[b * 256 + c]);
        else if (c < 288) v = bf2f(kgT[(c - 256) * 2048 + b]);
        else if (c < 320) v = bf2f(kiT[(c - 288) * 2048 + b]);
        else if (c < 352) v = bf2f(kcT[(c - 320) * 2048 + b]);
        else if (c < 384) v = bf2f(kpT[(c - 352) * 2048 + b]);
        else              v = clinn[b * 16 + (c - 384)];
        xs[i] = v;
    }
    __syncthreads();
    const int j = tid;
    float acc[8];
#pragma unroll
    for (int r = 0; r < 8; r++) acc[r] = 0.f;
    const float4* wrow = (const float4*)(W6 + (size_t)j * 400);
    for (int c = 0; c < 100; c++) {
        float4 wv = wrow[c];
        const float* wp = (const float*)&wv;
#pragma unroll
        for (int t = 0; t < 4; t++) {
            float w = wp[t];
            int k = c * 4 + t;
#pragma unroll
            for (int r = 0; r < 8; r++) acc[r] += w * xs[r * 400 + k];
        }
    }
    const float w7j = W7[j];
    const int lane = tid & 63, wave = tid >> 6;
    float t3 = w7j;
#pragma unroll
    for (int off = 32; off > 0; off >>= 1) t3 += __shfl_down(t3, off, 64);
    if (lane == 0) s3[wave] = t3;
#pragma unroll
    for (int r = 0; r < 8; r++) {
        float lp = sigm(acc[r]);
        float t1 = lp, t2 = lp * w7j;
#pragma unroll
        for (int off = 32; off > 0; off >>= 1) {
            t1 += __shfl_down(t1, off, 64);
            t2 += __shfl_down(t2, off, 64);
        }
        if (lane == 0) { s1[wave][r] = t1; s2[wave][r] = t2; }
    }
    __syncthreads();
    if (tid < 8) {
        float S1 = s1[0][tid] + s1[1][tid] + s1[2][tid] + s1[3][tid];
        float S2 = s2[0][tid] + s2[1][tid] + s2[2][tid] + s2[3][tid];
        float SW = s3[0] + s3[1] + s3[2] + s3[3];
        out[b0 + tid] = S2 - (S1 * (1.f / 256.f)) * SW;
    }
}

// ---------------------------------------------------------------------------
extern "C" void kernel_launch(void* const* d_in, const int* in_sizes, int n_in,
                              void* d_out, int out_size, void* d_ws, size_t ws_size,
                              hipStream_t stream) {
    const float* x_gene   = (const float*)d_in[0];
    const float* x_invmea = (const float*)d_in[1];
    const float* x_curv   = (const float*)d_in[2];
    const float* clinn    = (const float*)d_in[3];
    const float* Adj      = (const float*)d_in[4];
    const float* edge_m   = (const float*)d_in[5];
    const float* path_m   = (const float*)d_in[6];
    const float* tg_mask  = (const float*)d_in[7];
    const float* ti_mask  = (const float*)d_in[8];
    const float* tc_mask  = (const float*)d_in[9];
    const float* tp_mask  = (const float*)d_in[10];
    const float* W1 = (const float*)d_in[11];  const float* b1 = (const float*)d_in[12];
    const float* W2 = (const float*)d_in[13];  const float* b2 = (const float*)d_in[14];
    const float* W3 = (const float*)d_in[15];  const float* b3 = (const float*)d_in[16];
    const float* W4 = (const float*)d_in[17];  const float* b4 = (const float*)d_in[18];
    const float* W5 = (const float*)d_in[19];  const float* b5 = (const float*)d_in[20];
    const float* W6 = (const float*)d_in[21];
    const float* W7 = (const float*)d_in[22];
    const float* mp11 = (const float*)d_in[23];
    const float* mp12 = (const float*)d_in[24];
    const float* mp1  = (const float*)d_in[25];
    const float* mp21 = (const float*)d_in[26];
    const float* mp22 = (const float*)d_in[27];
    const float* mp2  = (const float*)d_in[28];
    const float* mp3  = (const float*)d_in[29];

    char* ws = (char*)d_ws;
    const float* nulf = nullptr;
    float* out = (float*)d_out;

    u16*  xTg   = (u16*)(ws + 0);            // [4096][2048]
    u16*  x3T   = (u16*)(ws + 0);            // [2048][2048] (after L1; xTg dead)
    u16*  xinvT = (u16*)(ws + 17301504);     // [4096][2048]
    u16*  xcvT  = (u16*)(ws + 34078720);     // [8192][2048]
    u16*  x1T   = (u16*)(ws + 67633152);     // [4096][2048]
    u16*  x2T   = (u16*)(ws + 84934656);     // [8192][2048]
    u16*  x3    = (u16*)(ws + 119537664);    // [2048][2048]
    unsigned* ell1 = (unsigned*)(ws + 127926272);  // 4 MiB
    unsigned* ell2 = (unsigned*)(ws + 132120576);  // 3 MiB
    unsigned* ell3 = (unsigned*)(ws + 135266304);  // 2.5 MiB
    int* cnt1 = (int*)(ws + 137887744);
    int* cnt2 = (int*)(ws + 137904128);
    int* cnt3 = (int*)(ws + 137936896);
    int* idxg = (int*)(ws + 137953280);      // 512 B (4 x 32 ints)
    int* idxi = idxg + 32;
    int* idxc = idxg + 64;
    int* idxp = idxg + 96;
    u16* kgT  = (u16*)(ws + 137957376);      // 128 KiB [32][2048]
    u16* kiT  = (u16*)(ws + 138088448);
    u16* kcT  = (u16*)(ws + 138219520);
    u16* kpT  = (u16*)(ws + 138350592);
    u16* w4b  = (u16*)(ws + 138481664);      // 1 MiB
    u16* w5b  = (u16*)(ws + 139530240);      // 128 KiB
    u16* x4   = (u16*)(ws + 139661312);      // 1 MiB
    u16* x5   = (u16*)(ws + 140709888);      // 1 MiB

    // ---- prep split into two halves (R7 structure, find reverted to 128) ---
    prep_part<<<11472, 256, 0, stream>>>(
        0, 7168, 0, 4304,
        Adj, W1, ell1, cnt1, edge_m, W2, ell2, cnt2, path_m, W3, ell3, cnt3,
        x_gene, x_invmea, x_curv, xTg, xinvT, xcvT,
        tg_mask, ti_mask, tc_mask, tp_mask, idxg, W4, w4b, W5, w5b);
    prep_part<<<11472, 256, 0, stream>>>(
        7168, 7168, 4304, 4304,
        Adj, W1, ell1, cnt1, edge_m, W2, ell2, cnt2, path_m, W3, ell3, cnt3,
        x_gene, x_invmea, x_curv, xTg, xinvT, xcvT,
        tg_mask, ti_mask, tc_mask, tp_mask, idxg, W4, w4b, W5, w5b);
    gatherFT<<<256, 256, 0, stream>>>(x_gene, 4096, idxg, kgT);

    // ---- L1 (BPL=8, slice-phased, fused kiT gather) ----
    spmm<8, 1, GSTR, 2048, GSTR><<<dim3(1024, 4), 256, 0, stream>>>(
        ell1, cnt1, xTg, x1T, b1, mp11, mp1, mp12, mp1, xinvT, idxi, kiT, 256);
    // ---- L2 (BPL=8, slice-phased, fused kcT gather) ----
    spmm<8, 2, GSTR, 2048, GSTR><<<dim3(2048, 4), 256, 0, stream>>>(
        ell2, cnt2, x1T, x2T, b2, mp21, mp2, mp22, mp2, xcvT, idxc, kcT, 96);
    // ---- L3 (slice-phased, fused kpT gather) ----
    spmm_ph<GSTR><<<dim3(512, 16), 256, 0, stream>>>(ell3, cnt3, x2T, x3T, b3,
                                                     mp3, idxp, kpT, 320);
    transpB<<<dim3(32, 32), 256, 0, stream>>>(x3T, x3, 2048, 2048);

    // ---- L4/L5 dense ----
    gemm_t<2, 2, 2, 2, 2, 4><<<dim3(4, 32), 256, 0, stream>>>(x3, w4b, x4, b4, 256, 2048);
    gemm_t<2, 2, 2, 2, 2, 4><<<dim3(4, 32), 256, 0, stream>>>(x4, w5b, x5, b5, 256, 256);

    // ---- fused xcat + tail ----
    tail_k<<<256, 256, 0, stream>>>(x5, kgT, kiT, kcT, kpT, clinn, W6, W7, out);
}